// Round 3
// baseline (350.089 us; speedup 1.0000x reference)
//
#include <hip/hip_runtime.h>

#define E_NUM 16
#define HDIM 1024
#define IDIM 1024
#define BM 128
#define BN 64
#define BK 32
#define BKP 40   // LDS row stride in shorts: 80 B = 5*16 -> every row 16B-aligned

typedef short bf16x8 __attribute__((ext_vector_type(8)));
typedef float f32x4 __attribute__((ext_vector_type(4)));

__device__ __forceinline__ unsigned short f2bf(float f) {
    unsigned u = __builtin_bit_cast(unsigned, f);
    return (unsigned short)((u + 0x7FFFu + ((u >> 16) & 1u)) >> 16);  // RNE
}

// ---------------- routing: bucket token ids by expert ----------------
__global__ void route_kernel(const int* __restrict__ eidx, int n_tok,
                             int* __restrict__ counts, int* __restrict__ tlist) {
    __shared__ int sc[E_NUM];
    int t = threadIdx.x;
    if (t < E_NUM) sc[t] = 0;
    __syncthreads();
    for (int n = t; n < n_tok; n += blockDim.x) {
        int e = eidx[n];
        if (e >= 0 && e < E_NUM) {
            int p = atomicAdd(&sc[e], 1);
            tlist[e * n_tok + p] = n;
        }
    }
    __syncthreads();
    if (t < E_NUM) counts[t] = sc[t];
}

// ---------------- phase 1: gate/up GEMMs + silu*mul -> inter (bf16) ----------------
__global__ __launch_bounds__(256) void gateup_kernel(
    const float* __restrict__ x, const float* __restrict__ Wg,
    const float* __restrict__ Wu, const int* __restrict__ counts,
    const int* __restrict__ tlist, unsigned short* __restrict__ inter, int n_tok)
{
    const int NT = IDIM / BN;                 // 16
    const int MT = (n_tok + BM - 1) / BM;     // 16
    int bid = blockIdx.x;
    int e = bid / (MT * NT);
    int rem = bid - e * (MT * NT);
    int mt = rem / NT;
    int nt = rem - mt * NT;
    int cnt = counts[e];
    if (cnt < 0) cnt = 0;
    if (cnt > n_tok) cnt = n_tok;
    int row0 = mt * BM;
    if (row0 >= cnt) return;
    int rows = cnt - row0; if (rows > BM) rows = BM;
    int n0 = nt * BN;

    __shared__ __align__(16) unsigned short As[BM][BKP];
    __shared__ __align__(16) unsigned short Bg[BN][BKP];
    __shared__ __align__(16) unsigned short Bu[BN][BKP];
    __shared__ int tok[BM];

    int t = threadIdx.x;
    // zero-init LDS (padding rows must be finite)
    {
        unsigned short* z0 = &As[0][0];
        for (int i = t; i < BM * BKP; i += 256) z0[i] = 0;
        unsigned short* z1 = &Bg[0][0];
        unsigned short* z2 = &Bu[0][0];
        for (int i = t; i < BN * BKP; i += 256) { z1[i] = 0; z2[i] = 0; }
    }
    for (int i = t; i < BM; i += 256)
        tok[i] = (i < rows) ? tlist[e * n_tok + row0 + i] : -1;
    __syncthreads();

    // staging coords
    int a_row = t >> 3;           // 0..31, +32p
    int a_c4  = (t & 7) * 4;      // 0..28
    int b_kk  = t >> 4;           // 0..15, +16p
    int b_i4  = (t & 15) * 4;     // 0..60

    int rtok[4];
    #pragma unroll
    for (int p = 0; p < 4; ++p) {
        int tk = tok[p * 32 + a_row];
        rtok[p] = (tk >= 0 && tk < n_tok) ? tk : -1;
    }

    const float* wg_b = Wg + (size_t)e * HDIM * IDIM + n0;
    const float* wu_b = Wu + (size_t)e * HDIM * IDIM + n0;

    int wid = t >> 6, lane = t & 63;
    int wm = wid >> 1, wn = wid & 1;
    int lr = lane & 15, lk = lane >> 4, lk8 = (lane >> 4) * 8;

    f32x4 accg[4][2] = {};
    f32x4 accu[4][2] = {};

    for (int k0 = 0; k0 < HDIM; k0 += BK) {
        __syncthreads();
        // stage A (gathered token rows), fp32 -> bf16
        #pragma unroll
        for (int p = 0; p < 4; ++p) {
            int r = p * 32 + a_row;
            float4 v = make_float4(0.f, 0.f, 0.f, 0.f);
            if (rtok[p] >= 0)
                v = *(const float4*)(x + (size_t)rtok[p] * HDIM + k0 + a_c4);
            ushort4 b;
            b.x = f2bf(v.x); b.y = f2bf(v.y); b.z = f2bf(v.z); b.w = f2bf(v.w);
            *(ushort4*)&As[r][a_c4] = b;
        }
        // stage B gate/up transposed into [BN][BK] (scalar stores)
        #pragma unroll
        for (int p = 0; p < 2; ++p) {
            int kk = p * 16 + b_kk;
            float4 g = *(const float4*)(wg_b + (size_t)(k0 + kk) * IDIM + b_i4);
            float4 u = *(const float4*)(wu_b + (size_t)(k0 + kk) * IDIM + b_i4);
            Bg[b_i4 + 0][kk] = f2bf(g.x); Bg[b_i4 + 1][kk] = f2bf(g.y);
            Bg[b_i4 + 2][kk] = f2bf(g.z); Bg[b_i4 + 3][kk] = f2bf(g.w);
            Bu[b_i4 + 0][kk] = f2bf(u.x); Bu[b_i4 + 1][kk] = f2bf(u.y);
            Bu[b_i4 + 2][kk] = f2bf(u.z); Bu[b_i4 + 3][kk] = f2bf(u.w);
        }
        __syncthreads();

        bf16x8 af[4];
        #pragma unroll
        for (int fm = 0; fm < 4; ++fm)
            af[fm] = *(const bf16x8*)&As[wm * 64 + fm * 16 + lr][lk8];
        #pragma unroll
        for (int fn = 0; fn < 2; ++fn) {
            int c = wn * 32 + fn * 16 + lr;
            bf16x8 bg = *(const bf16x8*)&Bg[c][lk8];
            bf16x8 bu = *(const bf16x8*)&Bu[c][lk8];
            #pragma unroll
            for (int fm = 0; fm < 4; ++fm) {
                accg[fm][fn] = __builtin_amdgcn_mfma_f32_16x16x32_bf16(af[fm], bg, accg[fm][fn], 0, 0, 0);
                accu[fm][fn] = __builtin_amdgcn_mfma_f32_16x16x32_bf16(af[fm], bu, accu[fm][fn], 0, 0, 0);
            }
        }
    }

    // epilogue: silu(g)*u -> bf16 inter[token][col]
    #pragma unroll
    for (int fm = 0; fm < 4; ++fm) {
        #pragma unroll
        for (int rr = 0; rr < 4; ++rr) {
            int row = wm * 64 + fm * 16 + lk * 4 + rr;
            if (row < rows) {
                int tk = tok[row];
                if (tk >= 0 && tk < n_tok) {
                    #pragma unroll
                    for (int fn = 0; fn < 2; ++fn) {
                        float g = accg[fm][fn][rr];
                        float u = accu[fm][fn][rr];
                        float s = g / (1.0f + __expf(-g)) * u;
                        inter[(size_t)tk * IDIM + n0 + wn * 32 + fn * 16 + lr] = f2bf(s);
                    }
                }
            }
        }
    }
}

// ---------------- phase 2: out = inter @ down^T (contract contiguous axis) ----------------
__global__ __launch_bounds__(256) void down_kernel(
    const unsigned short* __restrict__ inter, const float* __restrict__ Wd,
    const int* __restrict__ counts, const int* __restrict__ tlist,
    float* __restrict__ out, int n_tok)
{
    const int NT = HDIM / BN;                 // 16
    const int MT = (n_tok + BM - 1) / BM;     // 16
    int bid = blockIdx.x;
    int e = bid / (MT * NT);
    int rem = bid - e * (MT * NT);
    int mt = rem / NT;
    int nt = rem - mt * NT;
    int cnt = counts[e];
    if (cnt < 0) cnt = 0;
    if (cnt > n_tok) cnt = n_tok;
    int row0 = mt * BM;
    if (row0 >= cnt) return;
    int rows = cnt - row0; if (rows > BM) rows = BM;
    int j0 = nt * BN;

    __shared__ __align__(16) unsigned short As[BM][BKP];
    __shared__ __align__(16) unsigned short Bs[BN][BKP];
    __shared__ int tok[BM];

    int t = threadIdx.x;
    {
        unsigned short* z0 = &As[0][0];
        for (int i = t; i < BM * BKP; i += 256) z0[i] = 0;
        unsigned short* z1 = &Bs[0][0];
        for (int i = t; i < BN * BKP; i += 256) z1[i] = 0;
    }
    for (int i = t; i < BM; i += 256)
        tok[i] = (i < rows) ? tlist[e * n_tok + row0 + i] : -1;
    __syncthreads();

    int a_row = t >> 2;            // 0..63, +64p
    int a_u   = (t & 3) * 8;       // 0,8,16,24 -> 8 shorts (16 B) per granule
    int b_j   = t >> 3;            // 0..31, +32p
    int b_k4  = (t & 7) * 4;       // 0..28

    int rtok[2];
    {
        int tk0 = tok[a_row];
        int tk1 = tok[64 + a_row];
        rtok[0] = (tk0 >= 0 && tk0 < n_tok) ? tk0 : -1;
        rtok[1] = (tk1 >= 0 && tk1 < n_tok) ? tk1 : -1;
    }

    const float* wd_b = Wd + (size_t)e * IDIM * HDIM;

    int wid = t >> 6, lane = t & 63;
    int wm = wid >> 1, wn = wid & 1;
    int lr = lane & 15, lk = lane >> 4, lk8 = (lane >> 4) * 8;

    f32x4 acc[4][2] = {};

    for (int k0 = 0; k0 < IDIM; k0 += BK) {
        __syncthreads();
        // stage A from bf16 inter (gathered rows): uint4 = 8 bf16 -> FULL K coverage
        #pragma unroll
        for (int p = 0; p < 2; ++p) {
            int r = p * 64 + a_row;
            uint4 v = make_uint4(0u, 0u, 0u, 0u);
            if (rtok[p] >= 0)
                v = *(const uint4*)(inter + (size_t)rtok[p] * IDIM + k0 + a_u);
            *(uint4*)&As[r][a_u] = v;
        }
        // stage B: down[e][j][k] contiguous in k -> row-major copy + convert
        #pragma unroll
        for (int p = 0; p < 2; ++p) {
            int j = p * 32 + b_j;
            float4 w = *(const float4*)(wd_b + (size_t)(j0 + j) * HDIM + k0 + b_k4);
            ushort4 b;
            b.x = f2bf(w.x); b.y = f2bf(w.y); b.z = f2bf(w.z); b.w = f2bf(w.w);
            *(ushort4*)&Bs[j][b_k4] = b;
        }
        __syncthreads();

        bf16x8 af[4];
        #pragma unroll
        for (int fm = 0; fm < 4; ++fm)
            af[fm] = *(const bf16x8*)&As[wm * 64 + fm * 16 + lr][lk8];
        #pragma unroll
        for (int fn = 0; fn < 2; ++fn) {
            bf16x8 bv = *(const bf16x8*)&Bs[wn * 32 + fn * 16 + lr][lk8];
            #pragma unroll
            for (int fm = 0; fm < 4; ++fm)
                acc[fm][fn] = __builtin_amdgcn_mfma_f32_16x16x32_bf16(af[fm], bv, acc[fm][fn], 0, 0, 0);
        }
    }

    #pragma unroll
    for (int fm = 0; fm < 4; ++fm) {
        #pragma unroll
        for (int rr = 0; rr < 4; ++rr) {
            int row = wm * 64 + fm * 16 + lk * 4 + rr;
            if (row < rows) {
                int tk = tok[row];
                if (tk >= 0 && tk < n_tok) {
                    #pragma unroll
                    for (int fn = 0; fn < 2; ++fn)
                        out[(size_t)tk * HDIM + j0 + wn * 32 + fn * 16 + lr] = acc[fm][fn][rr];
                }
            }
        }
    }
}

extern "C" void kernel_launch(void* const* d_in, const int* in_sizes, int n_in,
                              void* d_out, int out_size, void* d_ws, size_t ws_size,
                              hipStream_t stream) {
    const float* x  = (const float*)d_in[0];
    const int* eidx = (const int*)d_in[1];
    const float* Wg = (const float*)d_in[2];
    const float* Wu = (const float*)d_in[3];
    const float* Wd = (const float*)d_in[4];
    float* out = (float*)d_out;
    int n_tok = in_sizes[1];   // B*S = 2048

    char* ws = (char*)d_ws;
    int* counts          = (int*)ws;                  // E ints
    int* tlist           = (int*)(ws + 1024);         // E * n_tok ints (128 KB)
    unsigned short* inter = (unsigned short*)(ws + (1 << 18));  // n_tok * IDIM bf16 (4 MB)

    route_kernel<<<1, 256, 0, stream>>>(eidx, n_tok, counts, tlist);
    int MT = (n_tok + BM - 1) / BM;
    gateup_kernel<<<E_NUM * MT * (IDIM / BN), 256, 0, stream>>>(x, Wg, Wu, counts, tlist, inter, n_tok);
    down_kernel<<<E_NUM * MT * (HDIM / BN), 256, 0, stream>>>(inter, Wd, counts, tlist, out, n_tok);
}